// Round 2
// baseline (517.589 us; speedup 1.0000x reference)
//
#include <hip/hip_runtime.h>
#include <hip/hip_fp16.h>
#include <math.h>

#define DD 128
#define CAP 64   // max facts per tail bucket; Poisson(10) => P(overflow) ~ 1e-30

typedef _Float16 half_t;
typedef __attribute__((ext_vector_type(8))) _Float16 half8;
typedef __attribute__((ext_vector_type(4))) float floatx4;

#define LDW 136  // 128 + 8 f16 pad: frag rows land 4 banks apart -> 2-way alias only (free)

// packed relu: x * (x > 0)  — ROCm 7.2 has no __hmax2
__device__ __forceinline__ __half2 relu2(__half2 x) {
    return __hmul2(x, __hgt2(x, __float2half2_rn(0.f)));
}

// DPP-fused add: t += dpp(t, CTRL); pure VALU, no LDS pipe.
template <int CTRL>
__device__ __forceinline__ float dpp_add(float x) {
    int y = __builtin_amdgcn_update_dpp(0, __float_as_int(x), CTRL, 0xf, 0xf, true);
    return x + __int_as_float(y);
}

// ---------------- one-time: W[k][n] f32 -> WT[n][k] f16 (4 matrices) ---------
__global__ void wt4(const float* __restrict__ W0, const float* __restrict__ W1,
                    const float* __restrict__ W2, const float* __restrict__ W3,
                    half_t* __restrict__ T0, half_t* __restrict__ T1,
                    half_t* __restrict__ T2, half_t* __restrict__ T3) {
    const float* W = blockIdx.x == 0 ? W0 : blockIdx.x == 1 ? W1 : blockIdx.x == 2 ? W2 : W3;
    half_t* T      = blockIdx.x == 0 ? T0 : blockIdx.x == 1 ? T1 : blockIdx.x == 2 ? T2 : T3;
    for (int i = threadIdx.x; i < DD * DD; i += blockDim.x) {
        int n = i >> 7, k = i & 127;
        T[i] = (half_t)W[(size_t)k * DD + n];
    }
}

// ---------------- MFMA GEMM: Out[M x 128] = gather(A) @ W (+bias) ------------
__global__ __launch_bounds__(256) void gemm_mfma(
    const float* __restrict__ table, const int* __restrict__ idx, int idxAdd, int M,
    const half_t* __restrict__ WT_g, const float* __restrict__ bias,
    float* __restrict__ OutF, __half* __restrict__ OutH) {
    __shared__ half_t WT[DD * LDW];
    __shared__ half_t As[64 * LDW];
    int tid = threadIdx.x;
    int lane = tid & 63;
    int w = tid >> 6;
    int rowf = lane & 15;
    int kgrp = (lane >> 4) * 8;

    for (int i = tid; i < 2048; i += 256) {
        int n = i >> 4, ch = i & 15;
        *(half8*)(WT + n * LDW + ch * 8) = *(const half8*)(WT_g + n * DD + ch * 8);
    }
    int tileM = blockIdx.x * 64;
    for (int i = tid; i < 2048; i += 256) {
        int row = i >> 5, c4 = i & 31;
        int gr = tileM + row;
        float4 v = make_float4(0.f, 0.f, 0.f, 0.f);
        if (gr < M) {
            int src = idx ? (idx[gr] + idxAdd) : gr;
            v = *(const float4*)(table + (size_t)src * DD + c4 * 4);
        }
        __half2 h01 = __floats2half2_rn(v.x, v.y);
        __half2 h23 = __floats2half2_rn(v.z, v.w);
        *(uint2*)(As + row * LDW + c4 * 4) = make_uint2(*(unsigned*)&h01, *(unsigned*)&h23);
    }
    __syncthreads();

    floatx4 acc[8];
#pragma unroll
    for (int t = 0; t < 8; t++) acc[t] = (floatx4){0.f, 0.f, 0.f, 0.f};
    const half_t* ap = As + (w * 16 + rowf) * LDW + kgrp;
    const half_t* bp0 = WT + rowf * LDW + kgrp;
#pragma unroll
    for (int kk = 0; kk < DD; kk += 32) {
        half8 a = *(const half8*)(ap + kk);
#pragma unroll
        for (int t = 0; t < 8; t++) {
            half8 b = *(const half8*)(bp0 + t * 16 * LDW + kk);
            acc[t] = __builtin_amdgcn_mfma_f32_16x16x32_f16(a, b, acc[t], 0, 0, 0);
        }
    }
    int orow = tileM + w * 16 + (lane >> 4) * 4;
#pragma unroll
    for (int t = 0; t < 8; t++) {
        int col = t * 16 + rowf;
        float bv = bias ? bias[col] : 0.f;
#pragma unroll
        for (int i = 0; i < 4; i++) {
            int gr = orow + i;
            if (gr < M) {
                float o = acc[t][i] + bv;
                if (OutF) OutF[(size_t)gr * DD + col] = o;
                if (OutH) OutH[(size_t)gr * DD + col] = __float2half(o);
            }
        }
    }
}

// ---------------- MFMA GEMM, packed-f16 epilogue -----------------------------
// Packed[row] = { f16(A[row][0..127]) , f16((A@W)[row][0..127]) }  (512 B/row)
__global__ __launch_bounds__(256) void gemm_pack_mfma(
    const float* __restrict__ table, int M,
    const half_t* __restrict__ WT_g, __half* __restrict__ Packed) {
    __shared__ half_t WT[DD * LDW];
    __shared__ half_t As[64 * LDW];
    int tid = threadIdx.x;
    int lane = tid & 63;
    int w = tid >> 6;
    int rowf = lane & 15;
    int kgrp = (lane >> 4) * 8;

    for (int i = tid; i < 2048; i += 256) {
        int n = i >> 4, ch = i & 15;
        *(half8*)(WT + n * LDW + ch * 8) = *(const half8*)(WT_g + n * DD + ch * 8);
    }
    int tileM = blockIdx.x * 64;
    for (int i = tid; i < 2048; i += 256) {
        int row = i >> 5, c4 = i & 31;
        int gr = tileM + row;
        float4 v = make_float4(0.f, 0.f, 0.f, 0.f);
        if (gr < M) v = *(const float4*)(table + (size_t)gr * DD + c4 * 4);
        __half2 h01 = __floats2half2_rn(v.x, v.y);
        __half2 h23 = __floats2half2_rn(v.z, v.w);
        uint2 u = make_uint2(*(unsigned*)&h01, *(unsigned*)&h23);
        *(uint2*)(As + row * LDW + c4 * 4) = u;
        if (gr < M) *(uint2*)(Packed + (size_t)gr * 256 + c4 * 4) = u;  // A-half of packed row
    }
    __syncthreads();

    floatx4 acc[8];
#pragma unroll
    for (int t = 0; t < 8; t++) acc[t] = (floatx4){0.f, 0.f, 0.f, 0.f};
    const half_t* ap = As + (w * 16 + rowf) * LDW + kgrp;
    const half_t* bp0 = WT + rowf * LDW + kgrp;
#pragma unroll
    for (int kk = 0; kk < DD; kk += 32) {
        half8 a = *(const half8*)(ap + kk);
#pragma unroll
        for (int t = 0; t < 8; t++) {
            half8 b = *(const half8*)(bp0 + t * 16 * LDW + kk);
            acc[t] = __builtin_amdgcn_mfma_f32_16x16x32_f16(a, b, acc[t], 0, 0, 0);
        }
    }
    int orow = tileM + w * 16 + (lane >> 4) * 4;
#pragma unroll
    for (int t = 0; t < 8; t++) {
        int col = t * 16 + rowf;
#pragma unroll
        for (int i = 0; i < 4; i++) {
            int gr = orow + i;
            if (gr < M) Packed[(size_t)gr * 256 + 128 + col] = __float2half(acc[t][i]);
        }
    }
}

// ---------------- dense alpha pass over E facts ------------------------------
// 2 facts per wave: lanes 0-31 fact e0, lanes 32-63 fact e0+1. 4 cols/lane.
// alpha_e = sigmoid( sum_c relu(pre_c) * wa_c + wb ), pre from packed 2nd halves.
// Reduce via DPP row_shr(1,2,4,8) + row_bcast15: lane31/63 hold the 32-sums.
__global__ __launch_bounds__(256) void alpha_kernel(
    const __half* __restrict__ HB, const __half* __restrict__ RB,
    const __half* __restrict__ QB, const int* __restrict__ facts,
    const float* __restrict__ wa, const float* __restrict__ wa_b,
    __half* __restrict__ alphaH, int E) {
    int tid = threadIdx.x;
    int lane = tid & 63;
    int wv = blockIdx.x * 4 + (tid >> 6);
    int e = wv * 2 + (lane >> 5);
    bool valid = e < E;
    int ec = valid ? e : (E - 1);
    int c = (lane & 31) * 4;

    int2 bn = *(const int2*)(facts + ec * 6);      // {b, n}
    int r = facts[ec * 6 + 3];
    int b_ = bn.x, n_ = bn.y;

    // second halves: pre = h@Ws + hr@Wr + (q@Wqr + bias)
    uint2 hu = *(const uint2*)(HB + n_ * 256 + 128 + c);
    uint2 ru = *(const uint2*)(RB + (r + 1) * 256 + 128 + c);
    uint2 qu = *(const uint2*)(QB + b_ * DD + c);
    __half2 h2a = *(__half2*)&hu.x, h2b = *(__half2*)&hu.y;
    __half2 r2a = *(__half2*)&ru.x, r2b = *(__half2*)&ru.y;
    __half2 q2a = *(__half2*)&qu.x, q2b = *(__half2*)&qu.y;

    float4 wv4 = *(const float4*)(wa + c);
    __half2 wa2a = __halves2half2(__float2half(wv4.x), __float2half(wv4.y));
    __half2 wa2b = __halves2half2(__float2half(wv4.z), __float2half(wv4.w));

    __half2 p2a = relu2(__hadd2(__hadd2(h2a, r2a), q2a));
    __half2 p2b = relu2(__hadd2(__hadd2(h2b, r2b), q2b));
    __half2 t2 = __hfma2(p2a, wa2a, __hmul2(p2b, wa2b));
    float t = __half2float(__low2half(t2)) + __half2float(__high2half(t2));

    t = dpp_add<0x111>(t);   // row_shr:1
    t = dpp_add<0x112>(t);   // row_shr:2
    t = dpp_add<0x114>(t);   // row_shr:4
    t = dpp_add<0x118>(t);   // row_shr:8  -> lane15/47 have row sums
    t = dpp_add<0x142>(t);   // row_bcast15 -> lane31/63 have 32-lane sums

    float al = 1.f / (1.f + __expf(-(t + wa_b[0])));
    if (((lane & 31) == 31) && valid) alphaH[e] = __float2half(al);
}

// ---------------- scatter into fixed-capacity buckets (packs alpha) ----------
// meta.y = RB_row(9b) | alpha_f16 << 16
__global__ void scatter_kernel(const int* __restrict__ facts, const int* __restrict__ tail,
                               const __half* __restrict__ alphaH,
                               int* __restrict__ cursor, int2* __restrict__ meta, int E) {
    int e = blockIdx.x * blockDim.x + threadIdx.x;
    if (e >= E) return;
    int n = facts[e * 6 + 1];
    int r = facts[e * 6 + 3];
    int t = tail[e];
    unsigned ab = __half_as_ushort(alphaH[e]);
    int slot = atomicAdd(&cursor[t], 1);
    if (slot < CAP) meta[(size_t)t * CAP + slot] = make_int2(n, (r + 1) | (int)(ab << 16));
}

// ---------------- light segment aggregation ----------------------------------
// one wave per segment, all 64 lanes message role, 2 cols/lane.
__global__ __launch_bounds__(256) void agg_lite(
    const __half* __restrict__ HB, const __half* __restrict__ RB,
    const int2* __restrict__ meta, const int* __restrict__ cursor,
    float* __restrict__ agg, int T) {
    int w = threadIdx.x >> 6;
    int lane = threadIdx.x & 63;
    int seg = blockIdx.x * 4 + w;
    if (seg >= T) return;
    int cnt = cursor[seg];
    if (cnt > CAP) cnt = CAP;
    const int2* mp = meta + seg * CAP;
    int co = lane * 2;
    __half2 acc = __float2half2_rn(0.f);

#define FB(m)                                                                  \
    {                                                                          \
        int n_ = (m).x;                                                        \
        int rr = (m).y & 0xFFFF;                                               \
        __half al = __ushort_as_half((unsigned short)((unsigned)(m).y >> 16)); \
        unsigned hu = *(const unsigned*)(HB + n_ * 256 + co);                  \
        unsigned ru = *(const unsigned*)(RB + rr * 256 + co);                  \
        __half2 s = __hadd2(*(__half2*)&hu, *(__half2*)&ru);                   \
        acc = __hfma2(__half2half2(al), s, acc);                               \
    }

    int i = 0;
    for (; i + 1 < cnt; i += 2) {
        int2 m0 = mp[i];
        int2 m1 = mp[i + 1];
        FB(m0);
        FB(m1);
    }
    if (i < cnt) {
        int2 m0 = mp[i];
        FB(m0);
    }
#undef FB

    float2 o;
    o.x = __half2float(__low2half(acc));
    o.y = __half2float(__high2half(acc));
    *(float2*)(agg + seg * DD + co) = o;
}

extern "C" void kernel_launch(void* const* d_in, const int* in_sizes, int n_in,
                              void* d_out, int out_size, void* d_ws, size_t ws_size,
                              hipStream_t stream) {
    const float* hidden    = (const float*)d_in[0];
    const float* rel_table = (const float*)d_in[1];
    const float* Ws        = (const float*)d_in[2];
    const float* Wr        = (const float*)d_in[3];
    const float* Wqr_w     = (const float*)d_in[4];
    const float* Wqr_b     = (const float*)d_in[5];
    const float* wa_w      = (const float*)d_in[6];
    const float* wa_b      = (const float*)d_in[7];
    const float* Wh        = (const float*)d_in[8];
    const int* query_rel   = (const int*)d_in[9];
    const int* facts       = (const int*)d_in[10];
    const int* tail_index  = (const int*)d_in[11];

    int N     = in_sizes[0] / DD;   // 200000
    int Rrows = in_sizes[1] / DD;   // 481
    int B     = in_sizes[9];        // 512
    int E     = in_sizes[11];       // 1000000
    int T     = in_sizes[12];       // 100000

    char* ws = (char*)d_ws;
    size_t off = 0;
    auto alloc = [&](size_t bytes) -> void* {
        void* p = ws + off;
        off += (bytes + 255) & ~(size_t)255;
        return p;
    };
    __half* HB  = (__half*)alloc((size_t)N * 256 * 2);      // 102.4 MB
    __half* RB  = (__half*)alloc((size_t)Rrows * 256 * 2);  // 246 KB
    __half* QB  = (__half*)alloc((size_t)B * DD * 2);       // 128 KB
    int* cursor = (int*)alloc((size_t)T * 4);               // 400 KB
    int2* meta  = (int2*)alloc((size_t)T * CAP * 8);        // 51.2 MB
    float* agg  = (float*)alloc((size_t)T * DD * 4);        // 51.2 MB
    half_t* WsT  = (half_t*)alloc((size_t)DD * DD * 2);     // 32 KB
    half_t* WrT  = (half_t*)alloc((size_t)DD * DD * 2);
    half_t* WqrT = (half_t*)alloc((size_t)DD * DD * 2);
    half_t* WhT  = (half_t*)alloc((size_t)DD * DD * 2);
    __half* alphaH = (__half*)alloc((size_t)E * 2);         // 2 MB

    (void)hipMemsetAsync(cursor, 0, (size_t)T * 4, stream);

    // f16 transposed weights (one tiny launch)
    wt4<<<4, 256, 0, stream>>>(Ws, Wr, Wqr_w, Wh, WsT, WrT, WqrT, WhT);

    // HB = {f16(hidden) || f16(hidden @ Ws)}
    gemm_pack_mfma<<<(N + 63) / 64, 256, 0, stream>>>(hidden, N, WsT, HB);
    // RB = {f16(rel_table) || f16(rel_table @ Wr)}
    gemm_pack_mfma<<<(Rrows + 63) / 64, 256, 0, stream>>>(rel_table, Rrows, WrT, RB);
    // QB = f16(rel_table[query_rel+1] @ Wqr_w + Wqr_b)
    gemm_mfma<<<(B + 63) / 64, 256, 0, stream>>>(rel_table, query_rel, 1, B,
                                                 WqrT, Wqr_b, nullptr, QB);

    // alpha for every fact (dense, perfectly balanced)
    alpha_kernel<<<(E + 7) / 8, 256, 0, stream>>>(HB, RB, QB, facts, wa_w, wa_b,
                                                  alphaH, E);

    scatter_kernel<<<(E + 255) / 256, 256, 0, stream>>>(facts, tail_index, alphaH,
                                                        cursor, meta, E);

    agg_lite<<<(T + 3) / 4, 256, 0, stream>>>(HB, RB, meta, cursor, agg, T);

    // out = agg @ Wh  (f16 inputs are exact: agg came from __half accumulators)
    gemm_mfma<<<(T + 63) / 64, 256, 0, stream>>>(agg, nullptr, 0, T, WhT, nullptr,
                                                 (float*)d_out, nullptr);
}

// Round 3
// 472.296 us; speedup vs baseline: 1.0959x; 1.0959x over previous
//
#include <hip/hip_runtime.h>
#include <hip/hip_fp16.h>
#include <math.h>

#define DD 128
#define CAP 64   // max facts per tail bucket; Poisson(10) => P(overflow) ~ 1e-30

typedef _Float16 half_t;
typedef __attribute__((ext_vector_type(8))) _Float16 half8;
typedef __attribute__((ext_vector_type(4))) float floatx4;

#define LDW 136  // 128 + 8 f16 pad: frag rows land 4 banks apart -> 2-way alias only (free)

// packed relu: x * (x > 0)  — ROCm 7.2 has no __hmax2
__device__ __forceinline__ __half2 relu2(__half2 x) {
    return __hmul2(x, __hgt2(x, __float2half2_rn(0.f)));
}

// DPP-fused add: t += dpp(t, CTRL); pure VALU, no LDS pipe.
template <int CTRL>
__device__ __forceinline__ float dpp_add(float x) {
    int y = __builtin_amdgcn_update_dpp(0, __float_as_int(x), CTRL, 0xf, 0xf, true);
    return x + __int_as_float(y);
}

// ---------------- one-time: W[k][n] f32 -> WT[n][k] f16 (4 matrices) ---------
__global__ void wt4(const float* __restrict__ W0, const float* __restrict__ W1,
                    const float* __restrict__ W2, const float* __restrict__ W3,
                    half_t* __restrict__ T0, half_t* __restrict__ T1,
                    half_t* __restrict__ T2, half_t* __restrict__ T3) {
    const float* W = blockIdx.x == 0 ? W0 : blockIdx.x == 1 ? W1 : blockIdx.x == 2 ? W2 : W3;
    half_t* T      = blockIdx.x == 0 ? T0 : blockIdx.x == 1 ? T1 : blockIdx.x == 2 ? T2 : T3;
    for (int i = threadIdx.x; i < DD * DD; i += blockDim.x) {
        int n = i >> 7, k = i & 127;
        T[i] = (half_t)W[(size_t)k * DD + n];
    }
}

// ---------------- MFMA GEMM: Out[M x 128] = gather(A) @ W (+bias) ------------
__global__ __launch_bounds__(256) void gemm_mfma(
    const float* __restrict__ table, const int* __restrict__ idx, int idxAdd, int M,
    const half_t* __restrict__ WT_g, const float* __restrict__ bias,
    float* __restrict__ OutF, __half* __restrict__ OutH) {
    __shared__ half_t WT[DD * LDW];
    __shared__ half_t As[64 * LDW];
    int tid = threadIdx.x;
    int lane = tid & 63;
    int w = tid >> 6;
    int rowf = lane & 15;
    int kgrp = (lane >> 4) * 8;

    for (int i = tid; i < 2048; i += 256) {
        int n = i >> 4, ch = i & 15;
        *(half8*)(WT + n * LDW + ch * 8) = *(const half8*)(WT_g + n * DD + ch * 8);
    }
    int tileM = blockIdx.x * 64;
    for (int i = tid; i < 2048; i += 256) {
        int row = i >> 5, c4 = i & 31;
        int gr = tileM + row;
        float4 v = make_float4(0.f, 0.f, 0.f, 0.f);
        if (gr < M) {
            int src = idx ? (idx[gr] + idxAdd) : gr;
            v = *(const float4*)(table + (size_t)src * DD + c4 * 4);
        }
        __half2 h01 = __floats2half2_rn(v.x, v.y);
        __half2 h23 = __floats2half2_rn(v.z, v.w);
        *(uint2*)(As + row * LDW + c4 * 4) = make_uint2(*(unsigned*)&h01, *(unsigned*)&h23);
    }
    __syncthreads();

    floatx4 acc[8];
#pragma unroll
    for (int t = 0; t < 8; t++) acc[t] = (floatx4){0.f, 0.f, 0.f, 0.f};
    const half_t* ap = As + (w * 16 + rowf) * LDW + kgrp;
    const half_t* bp0 = WT + rowf * LDW + kgrp;
#pragma unroll
    for (int kk = 0; kk < DD; kk += 32) {
        half8 a = *(const half8*)(ap + kk);
#pragma unroll
        for (int t = 0; t < 8; t++) {
            half8 b = *(const half8*)(bp0 + t * 16 * LDW + kk);
            acc[t] = __builtin_amdgcn_mfma_f32_16x16x32_f16(a, b, acc[t], 0, 0, 0);
        }
    }
    int orow = tileM + w * 16 + (lane >> 4) * 4;
#pragma unroll
    for (int t = 0; t < 8; t++) {
        int col = t * 16 + rowf;
        float bv = bias ? bias[col] : 0.f;
#pragma unroll
        for (int i = 0; i < 4; i++) {
            int gr = orow + i;
            if (gr < M) {
                float o = acc[t][i] + bv;
                if (OutF) OutF[(size_t)gr * DD + col] = o;
                if (OutH) OutH[(size_t)gr * DD + col] = __float2half(o);
            }
        }
    }
}

// ---------------- MFMA GEMM, packed-f16 epilogue -----------------------------
// Packed[row] = { f16(A[row][0..127]) , f16((A@W)[row][0..127]) }  (512 B/row)
__global__ __launch_bounds__(256) void gemm_pack_mfma(
    const float* __restrict__ table, int M,
    const half_t* __restrict__ WT_g, __half* __restrict__ Packed) {
    __shared__ half_t WT[DD * LDW];
    __shared__ half_t As[64 * LDW];
    int tid = threadIdx.x;
    int lane = tid & 63;
    int w = tid >> 6;
    int rowf = lane & 15;
    int kgrp = (lane >> 4) * 8;

    for (int i = tid; i < 2048; i += 256) {
        int n = i >> 4, ch = i & 15;
        *(half8*)(WT + n * LDW + ch * 8) = *(const half8*)(WT_g + n * DD + ch * 8);
    }
    int tileM = blockIdx.x * 64;
    for (int i = tid; i < 2048; i += 256) {
        int row = i >> 5, c4 = i & 31;
        int gr = tileM + row;
        float4 v = make_float4(0.f, 0.f, 0.f, 0.f);
        if (gr < M) v = *(const float4*)(table + (size_t)gr * DD + c4 * 4);
        __half2 h01 = __floats2half2_rn(v.x, v.y);
        __half2 h23 = __floats2half2_rn(v.z, v.w);
        uint2 u = make_uint2(*(unsigned*)&h01, *(unsigned*)&h23);
        *(uint2*)(As + row * LDW + c4 * 4) = u;
        if (gr < M) *(uint2*)(Packed + (size_t)gr * 256 + c4 * 4) = u;  // A-half of packed row
    }
    __syncthreads();

    floatx4 acc[8];
#pragma unroll
    for (int t = 0; t < 8; t++) acc[t] = (floatx4){0.f, 0.f, 0.f, 0.f};
    const half_t* ap = As + (w * 16 + rowf) * LDW + kgrp;
    const half_t* bp0 = WT + rowf * LDW + kgrp;
#pragma unroll
    for (int kk = 0; kk < DD; kk += 32) {
        half8 a = *(const half8*)(ap + kk);
#pragma unroll
        for (int t = 0; t < 8; t++) {
            half8 b = *(const half8*)(bp0 + t * 16 * LDW + kk);
            acc[t] = __builtin_amdgcn_mfma_f32_16x16x32_f16(a, b, acc[t], 0, 0, 0);
        }
    }
    int orow = tileM + w * 16 + (lane >> 4) * 4;
#pragma unroll
    for (int t = 0; t < 8; t++) {
        int col = t * 16 + rowf;
#pragma unroll
        for (int i = 0; i < 4; i++) {
            int gr = orow + i;
            if (gr < M) Packed[(size_t)gr * 256 + 128 + col] = __float2half(acc[t][i]);
        }
    }
}

// ---------------- fused alpha + scatter over E facts -------------------------
// 8 facts per wave: quarter-wave group g (16 lanes) handles facts e0+g and
// e0+g+4; each lane owns 8 cols (one uint4 per table). 6 gather-loads in
// flight per wave. DPP row_shr reduce within 16 lanes -> lane15 holds sum.
// Lane15 computes sigmoid, packs alpha into meta.y high 16 bits, scatters.
__global__ __launch_bounds__(256) void alpha_scatter(
    const __half* __restrict__ HB, const __half* __restrict__ RB,
    const __half* __restrict__ QB, const int* __restrict__ facts,
    const int* __restrict__ tail, const float* __restrict__ wa,
    const float* __restrict__ wa_b,
    int* __restrict__ cursor, int2* __restrict__ meta, int E) {
    int tid = threadIdx.x;
    int lane = tid & 63;
    int g = lane >> 4;       // quarter-wave group 0..3
    int cl = lane & 15;
    int c = cl * 8;          // 8 cols per lane
    int wv = (blockIdx.x * 256 + tid) >> 6;
    int e0 = wv * 8 + g;

    float4 wva = *(const float4*)(wa + c);
    float4 wvb = *(const float4*)(wa + c + 4);
    __half2 w0 = __halves2half2(__float2half(wva.x), __float2half(wva.y));
    __half2 w1 = __halves2half2(__float2half(wva.z), __float2half(wva.w));
    __half2 w2 = __halves2half2(__float2half(wvb.x), __float2half(wvb.y));
    __half2 w3 = __halves2half2(__float2half(wvb.z), __float2half(wvb.w));
    float wb = wa_b[0];

    int f0 = e0, f1 = e0 + 4;
    bool v0 = f0 < E, v1 = f1 < E;
    int fc0 = v0 ? f0 : 0, fc1 = v1 ? f1 : 0;

    // index + tail loads (L1/L2-resident streams)
    int2 bn0 = *(const int2*)(facts + (size_t)fc0 * 6);   // {b, n}
    int r0 = facts[(size_t)fc0 * 6 + 3];
    int tl0 = tail[fc0];
    int2 bn1 = *(const int2*)(facts + (size_t)fc1 * 6);
    int r1 = facts[(size_t)fc1 * 6 + 3];
    int tl1 = tail[fc1];

    // 6 independent 16B gathers in flight
    uint4 h0 = *(const uint4*)(HB + (size_t)bn0.y * 256 + 128 + c);
    uint4 rr0 = *(const uint4*)(RB + (size_t)(r0 + 1) * 256 + 128 + c);
    uint4 q0 = *(const uint4*)(QB + (size_t)bn0.x * DD + c);
    uint4 h1 = *(const uint4*)(HB + (size_t)bn1.y * 256 + 128 + c);
    uint4 rr1 = *(const uint4*)(RB + (size_t)(r1 + 1) * 256 + 128 + c);
    uint4 q1 = *(const uint4*)(QB + (size_t)bn1.x * DD + c);

#define DOT8(hu, ru, qu, out)                                                          \
    {                                                                                  \
        __half2 p0 = relu2(__hadd2(__hadd2(*(__half2*)&(hu).x, *(__half2*)&(ru).x),    \
                                   *(__half2*)&(qu).x));                               \
        __half2 p1 = relu2(__hadd2(__hadd2(*(__half2*)&(hu).y, *(__half2*)&(ru).y),    \
                                   *(__half2*)&(qu).y));                               \
        __half2 p2 = relu2(__hadd2(__hadd2(*(__half2*)&(hu).z, *(__half2*)&(ru).z),    \
                                   *(__half2*)&(qu).z));                               \
        __half2 p3 = relu2(__hadd2(__hadd2(*(__half2*)&(hu).w, *(__half2*)&(ru).w),    \
                                   *(__half2*)&(qu).w));                               \
        __half2 t2 = __hfma2(p1, w1, __hmul2(p0, w0));                                 \
        t2 = __hfma2(p2, w2, t2);                                                      \
        t2 = __hfma2(p3, w3, t2);                                                      \
        out = __half2float(__low2half(t2)) + __half2float(__high2half(t2));            \
    }
    float t0, t1;
    DOT8(h0, rr0, q0, t0);
    DOT8(h1, rr1, q1, t1);
#undef DOT8

    // 16-lane row reduce (f32): lane cl==15 of each row holds the sum
    t0 = dpp_add<0x111>(t0); t0 = dpp_add<0x112>(t0);
    t0 = dpp_add<0x114>(t0); t0 = dpp_add<0x118>(t0);
    t1 = dpp_add<0x111>(t1); t1 = dpp_add<0x112>(t1);
    t1 = dpp_add<0x114>(t1); t1 = dpp_add<0x118>(t1);

    if (cl == 15) {
        float a0 = 1.f / (1.f + __expf(-(t0 + wb)));
        float a1 = 1.f / (1.f + __expf(-(t1 + wb)));
        unsigned ab0 = (unsigned)__half_as_ushort(__float2half(a0));
        unsigned ab1 = (unsigned)__half_as_ushort(__float2half(a1));
        if (v0) {
            int slot = atomicAdd(&cursor[tl0], 1);
            if (slot < CAP)
                meta[(size_t)tl0 * CAP + slot] = make_int2(bn0.y, (r0 + 1) | (int)(ab0 << 16));
        }
        if (v1) {
            int slot = atomicAdd(&cursor[tl1], 1);
            if (slot < CAP)
                meta[(size_t)tl1 * CAP + slot] = make_int2(bn1.y, (r1 + 1) | (int)(ab1 << 16));
        }
    }
}

// ---------------- light segment aggregation ----------------------------------
// one wave per segment, 2 cols/lane, 4 facts in flight per iteration, f32 acc.
__global__ __launch_bounds__(256) void agg_lite(
    const __half* __restrict__ HB, const __half* __restrict__ RB,
    const int2* __restrict__ meta, const int* __restrict__ cursor,
    float* __restrict__ agg, int T) {
    int w = threadIdx.x >> 6;
    int lane = threadIdx.x & 63;
    int seg = blockIdx.x * 4 + w;
    if (seg >= T) return;
    int cnt = cursor[seg];
    if (cnt > CAP) cnt = CAP;
    const int2* mp = meta + (size_t)seg * CAP;
    int co = lane * 2;
    float ax = 0.f, ay = 0.f;

#define ACC(hu, ru, y_)                                                        \
    {                                                                          \
        __half2 s = __hadd2(*(__half2*)&(hu), *(__half2*)&(ru));               \
        float al =                                                             \
            __half2float(__ushort_as_half((unsigned short)((unsigned)(y_) >> 16))); \
        float2 sf = __half22float2(s);                                         \
        ax = fmaf(al, sf.x, ax);                                               \
        ay = fmaf(al, sf.y, ay);                                               \
    }

    int i = 0;
    for (; i + 3 < cnt; i += 4) {
        int4 ma = *(const int4*)(mp + i);      // facts i, i+1
        int4 mb = *(const int4*)(mp + i + 2);  // facts i+2, i+3
        unsigned h0 = *(const unsigned*)(HB + (size_t)ma.x * 256 + co);
        unsigned r0 = *(const unsigned*)(RB + (size_t)(ma.y & 0xFFFF) * 256 + co);
        unsigned h1 = *(const unsigned*)(HB + (size_t)ma.z * 256 + co);
        unsigned r1 = *(const unsigned*)(RB + (size_t)(ma.w & 0xFFFF) * 256 + co);
        unsigned h2 = *(const unsigned*)(HB + (size_t)mb.x * 256 + co);
        unsigned r2 = *(const unsigned*)(RB + (size_t)(mb.y & 0xFFFF) * 256 + co);
        unsigned h3 = *(const unsigned*)(HB + (size_t)mb.z * 256 + co);
        unsigned r3 = *(const unsigned*)(RB + (size_t)(mb.w & 0xFFFF) * 256 + co);
        ACC(h0, r0, ma.y);
        ACC(h1, r1, ma.w);
        ACC(h2, r2, mb.y);
        ACC(h3, r3, mb.w);
    }
    for (; i < cnt; i++) {
        int2 m = mp[i];
        unsigned hu = *(const unsigned*)(HB + (size_t)m.x * 256 + co);
        unsigned ru = *(const unsigned*)(RB + (size_t)(m.y & 0xFFFF) * 256 + co);
        ACC(hu, ru, m.y);
    }
#undef ACC

    *(float2*)(agg + (size_t)seg * DD + co) = make_float2(ax, ay);
}

extern "C" void kernel_launch(void* const* d_in, const int* in_sizes, int n_in,
                              void* d_out, int out_size, void* d_ws, size_t ws_size,
                              hipStream_t stream) {
    const float* hidden    = (const float*)d_in[0];
    const float* rel_table = (const float*)d_in[1];
    const float* Ws        = (const float*)d_in[2];
    const float* Wr        = (const float*)d_in[3];
    const float* Wqr_w     = (const float*)d_in[4];
    const float* Wqr_b     = (const float*)d_in[5];
    const float* wa_w      = (const float*)d_in[6];
    const float* wa_b      = (const float*)d_in[7];
    const float* Wh        = (const float*)d_in[8];
    const int* query_rel   = (const int*)d_in[9];
    const int* facts       = (const int*)d_in[10];
    const int* tail_index  = (const int*)d_in[11];

    int N     = in_sizes[0] / DD;   // 200000
    int Rrows = in_sizes[1] / DD;   // 481
    int B     = in_sizes[9];        // 512
    int E     = in_sizes[11];       // 1000000
    int T     = in_sizes[12];       // 100000

    char* ws = (char*)d_ws;
    size_t off = 0;
    auto alloc = [&](size_t bytes) -> void* {
        void* p = ws + off;
        off += (bytes + 255) & ~(size_t)255;
        return p;
    };
    __half* HB  = (__half*)alloc((size_t)N * 256 * 2);      // 102.4 MB
    __half* RB  = (__half*)alloc((size_t)Rrows * 256 * 2);  // 246 KB
    __half* QB  = (__half*)alloc((size_t)B * DD * 2);       // 128 KB
    int* cursor = (int*)alloc((size_t)T * 4);               // 400 KB
    int2* meta  = (int2*)alloc((size_t)T * CAP * 8);        // 51.2 MB
    float* agg  = (float*)alloc((size_t)T * DD * 4);        // 51.2 MB
    half_t* WsT  = (half_t*)alloc((size_t)DD * DD * 2);     // 32 KB
    half_t* WrT  = (half_t*)alloc((size_t)DD * DD * 2);
    half_t* WqrT = (half_t*)alloc((size_t)DD * DD * 2);
    half_t* WhT  = (half_t*)alloc((size_t)DD * DD * 2);

    (void)hipMemsetAsync(cursor, 0, (size_t)T * 4, stream);

    // f16 transposed weights (one tiny launch)
    wt4<<<4, 256, 0, stream>>>(Ws, Wr, Wqr_w, Wh, WsT, WrT, WqrT, WhT);

    // HB = {f16(hidden) || f16(hidden @ Ws)}
    gemm_pack_mfma<<<(N + 63) / 64, 256, 0, stream>>>(hidden, N, WsT, HB);
    // RB = {f16(rel_table) || f16(rel_table @ Wr)}
    gemm_pack_mfma<<<(Rrows + 63) / 64, 256, 0, stream>>>(rel_table, Rrows, WrT, RB);
    // QB = f16(rel_table[query_rel+1] @ Wqr_w + Wqr_b)
    gemm_mfma<<<(B + 63) / 64, 256, 0, stream>>>(rel_table, query_rel, 1, B,
                                                 WqrT, Wqr_b, nullptr, QB);

    // alpha + scatter fused: 8 facts/wave, 6 gathers in flight
    alpha_scatter<<<(E + 31) / 32, 256, 0, stream>>>(HB, RB, QB, facts, tail_index,
                                                     wa_w, wa_b, cursor, meta, E);

    agg_lite<<<(T + 3) / 4, 256, 0, stream>>>(HB, RB, meta, cursor, agg, T);

    // out = agg @ Wh
    gemm_mfma<<<(T + 63) / 64, 256, 0, stream>>>(agg, nullptr, 0, T, WhT, nullptr,
                                                 (float*)d_out, nullptr);
}

// Round 5
// 451.665 us; speedup vs baseline: 1.1460x; 1.0457x over previous
//
#include <hip/hip_runtime.h>
#include <hip/hip_fp16.h>
#include <math.h>

#define DD 128
#define CAP 64   // max facts per tail bucket; Poisson(10) => P(overflow) ~ 1e-30

typedef _Float16 half_t;
typedef __attribute__((ext_vector_type(8))) _Float16 half8;
typedef __attribute__((ext_vector_type(4))) float floatx4;

#define LDW 136  // 128 + 8 f16 pad: frag rows land 4 banks apart -> 2-way alias only (free)

// packed relu: x * (x > 0)  — ROCm 7.2 has no __hmax2
__device__ __forceinline__ __half2 relu2(__half2 x) {
    return __hmul2(x, __hgt2(x, __float2half2_rn(0.f)));
}

// DPP-fused add: t += dpp(t, CTRL); pure VALU, no LDS pipe.
template <int CTRL>
__device__ __forceinline__ float dpp_add(float x) {
    int y = __builtin_amdgcn_update_dpp(0, __float_as_int(x), CTRL, 0xf, 0xf, true);
    return x + __int_as_float(y);
}

// ---------------- one-time: W[k][n] f32 -> WT[n][k] f16 (4 matrices) ---------
__global__ void wt4(const float* __restrict__ W0, const float* __restrict__ W1,
                    const float* __restrict__ W2, const float* __restrict__ W3,
                    half_t* __restrict__ T0, half_t* __restrict__ T1,
                    half_t* __restrict__ T2, half_t* __restrict__ T3) {
    const float* W = blockIdx.x == 0 ? W0 : blockIdx.x == 1 ? W1 : blockIdx.x == 2 ? W2 : W3;
    half_t* T      = blockIdx.x == 0 ? T0 : blockIdx.x == 1 ? T1 : blockIdx.x == 2 ? T2 : T3;
    for (int i = threadIdx.x; i < DD * DD; i += blockDim.x) {
        int n = i >> 7, k = i & 127;
        T[i] = (half_t)W[(size_t)k * DD + n];
    }
}

// shared MFMA tile pass: acc over K=128 from As(row-tile) x WT(col-tile), then
// store f16 to Packed[gr*256 + halfOff + col].
__device__ __forceinline__ void mfma_pass_store(
    const half_t* As, const half_t* WT, int tileM, int M, int w, int lane,
    __half* Packed, int halfOff) {
    int rowf = lane & 15;
    int kgrp = (lane >> 4) * 8;
    floatx4 acc[8];
#pragma unroll
    for (int t = 0; t < 8; t++) acc[t] = (floatx4){0.f, 0.f, 0.f, 0.f};
    const half_t* ap = As + (w * 16 + rowf) * LDW + kgrp;
    const half_t* bp0 = WT + rowf * LDW + kgrp;
#pragma unroll
    for (int kk = 0; kk < DD; kk += 32) {
        half8 a = *(const half8*)(ap + kk);
#pragma unroll
        for (int t = 0; t < 8; t++) {
            half8 b = *(const half8*)(bp0 + t * 16 * LDW + kk);
            acc[t] = __builtin_amdgcn_mfma_f32_16x16x32_f16(a, b, acc[t], 0, 0, 0);
        }
    }
    int orow = tileM + w * 16 + (lane >> 4) * 4;
#pragma unroll
    for (int t = 0; t < 8; t++) {
        int col = t * 16 + rowf;
#pragma unroll
        for (int i = 0; i < 4; i++) {
            int gr = orow + i;
            if (gr < M) Packed[(size_t)gr * 256 + halfOff + col] = __float2half(acc[t][i]);
        }
    }
}

// ---------------- MFMA GEMM x2, packed-f16 epilogue --------------------------
// Packed[row] = { f16(A@W1)[0..127] , f16(A@W2)[0..127] }  (512 B/row)
// WT LDS buffer is reused sequentially: 52 KB total -> 3 blocks/CU.
__global__ __launch_bounds__(256) void gemm_pack2(
    const float* __restrict__ table, int M,
    const half_t* __restrict__ WT1_g, const half_t* __restrict__ WT2_g,
    __half* __restrict__ Packed) {
    __shared__ half_t WT[DD * LDW];
    __shared__ half_t As[64 * LDW];
    int tid = threadIdx.x;
    int lane = tid & 63;
    int w = tid >> 6;
    int tileM = blockIdx.x * 64;

    // A tile -> f16 LDS
    for (int i = tid; i < 2048; i += 256) {
        int row = i >> 5, c4 = i & 31;
        int gr = tileM + row;
        float4 v = make_float4(0.f, 0.f, 0.f, 0.f);
        if (gr < M) v = *(const float4*)(table + (size_t)gr * DD + c4 * 4);
        __half2 h01 = __floats2half2_rn(v.x, v.y);
        __half2 h23 = __floats2half2_rn(v.z, v.w);
        *(uint2*)(As + row * LDW + c4 * 4) = make_uint2(*(unsigned*)&h01, *(unsigned*)&h23);
    }
    // WT <- W1
    for (int i = tid; i < 2048; i += 256) {
        int n = i >> 4, ch = i & 15;
        *(half8*)(WT + n * LDW + ch * 8) = *(const half8*)(WT1_g + n * DD + ch * 8);
    }
    __syncthreads();
    mfma_pass_store(As, WT, tileM, M, w, lane, Packed, 0);
    __syncthreads();                 // all waves done reading WT(W1)
    // WT <- W2
    for (int i = tid; i < 2048; i += 256) {
        int n = i >> 4, ch = i & 15;
        *(half8*)(WT + n * LDW + ch * 8) = *(const half8*)(WT2_g + n * DD + ch * 8);
    }
    __syncthreads();
    mfma_pass_store(As, WT, tileM, M, w, lane, Packed, 128);
}

// ---------------- MFMA GEMM: Out[M x 128] = gather(A) @ W (+bias) ------------
__global__ __launch_bounds__(256) void gemm_mfma(
    const float* __restrict__ table, const int* __restrict__ idx, int idxAdd, int M,
    const half_t* __restrict__ WT_g, const float* __restrict__ bias,
    float* __restrict__ OutF, __half* __restrict__ OutH) {
    __shared__ half_t WT[DD * LDW];
    __shared__ half_t As[64 * LDW];
    int tid = threadIdx.x;
    int lane = tid & 63;
    int w = tid >> 6;
    int rowf = lane & 15;
    int kgrp = (lane >> 4) * 8;

    for (int i = tid; i < 2048; i += 256) {
        int n = i >> 4, ch = i & 15;
        *(half8*)(WT + n * LDW + ch * 8) = *(const half8*)(WT_g + n * DD + ch * 8);
    }
    int tileM = blockIdx.x * 64;
    for (int i = tid; i < 2048; i += 256) {
        int row = i >> 5, c4 = i & 31;
        int gr = tileM + row;
        float4 v = make_float4(0.f, 0.f, 0.f, 0.f);
        if (gr < M) {
            int src = idx ? (idx[gr] + idxAdd) : gr;
            v = *(const float4*)(table + (size_t)src * DD + c4 * 4);
        }
        __half2 h01 = __floats2half2_rn(v.x, v.y);
        __half2 h23 = __floats2half2_rn(v.z, v.w);
        *(uint2*)(As + row * LDW + c4 * 4) = make_uint2(*(unsigned*)&h01, *(unsigned*)&h23);
    }
    __syncthreads();

    floatx4 acc[8];
#pragma unroll
    for (int t = 0; t < 8; t++) acc[t] = (floatx4){0.f, 0.f, 0.f, 0.f};
    const half_t* ap = As + (w * 16 + rowf) * LDW + kgrp;
    const half_t* bp0 = WT + rowf * LDW + kgrp;
#pragma unroll
    for (int kk = 0; kk < DD; kk += 32) {
        half8 a = *(const half8*)(ap + kk);
#pragma unroll
        for (int t = 0; t < 8; t++) {
            half8 b = *(const half8*)(bp0 + t * 16 * LDW + kk);
            acc[t] = __builtin_amdgcn_mfma_f32_16x16x32_f16(a, b, acc[t], 0, 0, 0);
        }
    }
    int orow = tileM + w * 16 + (lane >> 4) * 4;
#pragma unroll
    for (int t = 0; t < 8; t++) {
        int col = t * 16 + rowf;
        float bv = bias ? bias[col] : 0.f;
#pragma unroll
        for (int i = 0; i < 4; i++) {
            int gr = orow + i;
            if (gr < M) {
                float o = acc[t][i] + bv;
                if (OutF) OutF[(size_t)gr * DD + col] = o;
                if (OutH) OutH[(size_t)gr * DD + col] = __float2half(o);
            }
        }
    }
}

// ---------------- fused alpha + scatter over E facts -------------------------
// 8 facts per wave: quarter-wave group g (16 lanes) handles facts e0+g and
// e0+g+4; each lane owns 8 cols (one uint4 per table). 6 gather-loads in
// flight per wave. DPP row_shr reduce within 16 lanes -> lane15 holds sum.
// Lane15 computes sigmoid, packs alpha into meta.y high 16 bits, scatters.
__global__ __launch_bounds__(256) void alpha_scatter(
    const __half* __restrict__ HB, const __half* __restrict__ RB,
    const __half* __restrict__ QB, const int* __restrict__ facts,
    const int* __restrict__ tail, const float* __restrict__ wa,
    const float* __restrict__ wa_b,
    int* __restrict__ cursor, int2* __restrict__ meta, int E) {
    int tid = threadIdx.x;
    int lane = tid & 63;
    int g = lane >> 4;       // quarter-wave group 0..3
    int cl = lane & 15;
    int c = cl * 8;          // 8 cols per lane
    int wv = (blockIdx.x * 256 + tid) >> 6;
    int e0 = wv * 8 + g;

    float4 wva = *(const float4*)(wa + c);
    float4 wvb = *(const float4*)(wa + c + 4);
    __half2 w0 = __halves2half2(__float2half(wva.x), __float2half(wva.y));
    __half2 w1 = __halves2half2(__float2half(wva.z), __float2half(wva.w));
    __half2 w2 = __halves2half2(__float2half(wvb.x), __float2half(wvb.y));
    __half2 w3 = __halves2half2(__float2half(wvb.z), __float2half(wvb.w));
    float wb = wa_b[0];

    int f0 = e0, f1 = e0 + 4;
    bool v0 = f0 < E, v1 = f1 < E;
    int fc0 = v0 ? f0 : 0, fc1 = v1 ? f1 : 0;

    // index + tail loads (L1/L2-resident streams)
    int2 bn0 = *(const int2*)(facts + (size_t)fc0 * 6);   // {b, n}
    int r0 = facts[(size_t)fc0 * 6 + 3];
    int tl0 = tail[fc0];
    int2 bn1 = *(const int2*)(facts + (size_t)fc1 * 6);
    int r1 = facts[(size_t)fc1 * 6 + 3];
    int tl1 = tail[fc1];

    // 6 independent 16B gathers in flight
    uint4 h0 = *(const uint4*)(HB + (size_t)bn0.y * 256 + 128 + c);
    uint4 rr0 = *(const uint4*)(RB + (size_t)(r0 + 1) * 256 + 128 + c);
    uint4 q0 = *(const uint4*)(QB + (size_t)bn0.x * DD + c);
    uint4 h1 = *(const uint4*)(HB + (size_t)bn1.y * 256 + 128 + c);
    uint4 rr1 = *(const uint4*)(RB + (size_t)(r1 + 1) * 256 + 128 + c);
    uint4 q1 = *(const uint4*)(QB + (size_t)bn1.x * DD + c);

#define DOT8(hu, ru, qu, out)                                                          \
    {                                                                                  \
        __half2 p0 = relu2(__hadd2(__hadd2(*(__half2*)&(hu).x, *(__half2*)&(ru).x),    \
                                   *(__half2*)&(qu).x));                               \
        __half2 p1 = relu2(__hadd2(__hadd2(*(__half2*)&(hu).y, *(__half2*)&(ru).y),    \
                                   *(__half2*)&(qu).y));                               \
        __half2 p2 = relu2(__hadd2(__hadd2(*(__half2*)&(hu).z, *(__half2*)&(ru).z),    \
                                   *(__half2*)&(qu).z));                               \
        __half2 p3 = relu2(__hadd2(__hadd2(*(__half2*)&(hu).w, *(__half2*)&(ru).w),    \
                                   *(__half2*)&(qu).w));                               \
        __half2 t2 = __hfma2(p1, w1, __hmul2(p0, w0));                                 \
        t2 = __hfma2(p2, w2, t2);                                                      \
        t2 = __hfma2(p3, w3, t2);                                                      \
        out = __half2float(__low2half(t2)) + __half2float(__high2half(t2));            \
    }
    float t0, t1;
    DOT8(h0, rr0, q0, t0);
    DOT8(h1, rr1, q1, t1);
#undef DOT8

    // 16-lane row reduce (f32): lane cl==15 of each row holds the sum
    t0 = dpp_add<0x111>(t0); t0 = dpp_add<0x112>(t0);
    t0 = dpp_add<0x114>(t0); t0 = dpp_add<0x118>(t0);
    t1 = dpp_add<0x111>(t1); t1 = dpp_add<0x112>(t1);
    t1 = dpp_add<0x114>(t1); t1 = dpp_add<0x118>(t1);

    if (cl == 15) {
        float a0 = 1.f / (1.f + __expf(-(t0 + wb)));
        float a1 = 1.f / (1.f + __expf(-(t1 + wb)));
        unsigned ab0 = (unsigned)__half_as_ushort(__float2half(a0));
        unsigned ab1 = (unsigned)__half_as_ushort(__float2half(a1));
        if (v0) {
            int slot = atomicAdd(&cursor[tl0], 1);
            if (slot < CAP)
                meta[(size_t)tl0 * CAP + slot] = make_int2(bn0.y, (r0 + 1) | (int)(ab0 << 16));
        }
        if (v1) {
            int slot = atomicAdd(&cursor[tl1], 1);
            if (slot < CAP)
                meta[(size_t)tl1 * CAP + slot] = make_int2(bn1.y, (r1 + 1) | (int)(ab1 << 16));
        }
    }
}

// ---------------- segment aggregation direct to output -----------------------
// out[t] = sum alpha * (hWh[n] + hrWh[r])  — first halves of HB/RB rows.
// one wave per segment, 2 cols/lane, 8 facts in flight per iteration, f32 acc.
__global__ __launch_bounds__(256) void agg_out(
    const __half* __restrict__ HB, const __half* __restrict__ RB,
    const int2* __restrict__ meta, const int* __restrict__ cursor,
    float* __restrict__ out, int T) {
    int w = threadIdx.x >> 6;
    int lane = threadIdx.x & 63;
    int seg = blockIdx.x * 4 + w;
    if (seg >= T) return;
    int cnt = cursor[seg];
    if (cnt > CAP) cnt = CAP;
    const int2* mp = meta + (size_t)seg * CAP;
    int co = lane * 2;
    float ax = 0.f, ay = 0.f;

#define ACC(hu, ru, y_)                                                        \
    {                                                                          \
        __half2 s = __hadd2(*(__half2*)&(hu), *(__half2*)&(ru));               \
        float al =                                                             \
            __half2float(__ushort_as_half((unsigned short)((unsigned)(y_) >> 16))); \
        float2 sf = __half22float2(s);                                         \
        ax = fmaf(al, sf.x, ax);                                               \
        ay = fmaf(al, sf.y, ay);                                               \
    }

    int i = 0;
    for (; i + 7 < cnt; i += 8) {
        int4 ma = *(const int4*)(mp + i);
        int4 mb = *(const int4*)(mp + i + 2);
        int4 mc = *(const int4*)(mp + i + 4);
        int4 md = *(const int4*)(mp + i + 6);
        unsigned h0 = *(const unsigned*)(HB + (size_t)ma.x * 256 + co);
        unsigned r0 = *(const unsigned*)(RB + (size_t)(ma.y & 0xFFFF) * 256 + co);
        unsigned h1 = *(const unsigned*)(HB + (size_t)ma.z * 256 + co);
        unsigned r1 = *(const unsigned*)(RB + (size_t)(ma.w & 0xFFFF) * 256 + co);
        unsigned h2 = *(const unsigned*)(HB + (size_t)mb.x * 256 + co);
        unsigned r2 = *(const unsigned*)(RB + (size_t)(mb.y & 0xFFFF) * 256 + co);
        unsigned h3 = *(const unsigned*)(HB + (size_t)mb.z * 256 + co);
        unsigned r3 = *(const unsigned*)(RB + (size_t)(mb.w & 0xFFFF) * 256 + co);
        unsigned h4 = *(const unsigned*)(HB + (size_t)mc.x * 256 + co);
        unsigned r4 = *(const unsigned*)(RB + (size_t)(mc.y & 0xFFFF) * 256 + co);
        unsigned h5 = *(const unsigned*)(HB + (size_t)mc.z * 256 + co);
        unsigned r5 = *(const unsigned*)(RB + (size_t)(mc.w & 0xFFFF) * 256 + co);
        unsigned h6 = *(const unsigned*)(HB + (size_t)md.x * 256 + co);
        unsigned r6 = *(const unsigned*)(RB + (size_t)(md.y & 0xFFFF) * 256 + co);
        unsigned h7 = *(const unsigned*)(HB + (size_t)md.z * 256 + co);
        unsigned r7 = *(const unsigned*)(RB + (size_t)(md.w & 0xFFFF) * 256 + co);
        ACC(h0, r0, ma.y); ACC(h1, r1, ma.w);
        ACC(h2, r2, mb.y); ACC(h3, r3, mb.w);
        ACC(h4, r4, mc.y); ACC(h5, r5, mc.w);
        ACC(h6, r6, md.y); ACC(h7, r7, md.w);
    }
    for (; i + 3 < cnt; i += 4) {
        int4 ma = *(const int4*)(mp + i);
        int4 mb = *(const int4*)(mp + i + 2);
        unsigned h0 = *(const unsigned*)(HB + (size_t)ma.x * 256 + co);
        unsigned r0 = *(const unsigned*)(RB + (size_t)(ma.y & 0xFFFF) * 256 + co);
        unsigned h1 = *(const unsigned*)(HB + (size_t)ma.z * 256 + co);
        unsigned r1 = *(const unsigned*)(RB + (size_t)(ma.w & 0xFFFF) * 256 + co);
        unsigned h2 = *(const unsigned*)(HB + (size_t)mb.x * 256 + co);
        unsigned r2 = *(const unsigned*)(RB + (size_t)(mb.y & 0xFFFF) * 256 + co);
        unsigned h3 = *(const unsigned*)(HB + (size_t)mb.z * 256 + co);
        unsigned r3 = *(const unsigned*)(RB + (size_t)(mb.w & 0xFFFF) * 256 + co);
        ACC(h0, r0, ma.y); ACC(h1, r1, ma.w);
        ACC(h2, r2, mb.y); ACC(h3, r3, mb.w);
    }
    for (; i < cnt; i++) {
        int2 m = mp[i];
        unsigned hu = *(const unsigned*)(HB + (size_t)m.x * 256 + co);
        unsigned ru = *(const unsigned*)(RB + (size_t)(m.y & 0xFFFF) * 256 + co);
        ACC(hu, ru, m.y);
    }
#undef ACC

    *(float2*)(out + (size_t)seg * DD + co) = make_float2(ax, ay);
}

extern "C" void kernel_launch(void* const* d_in, const int* in_sizes, int n_in,
                              void* d_out, int out_size, void* d_ws, size_t ws_size,
                              hipStream_t stream) {
    const float* hidden    = (const float*)d_in[0];
    const float* rel_table = (const float*)d_in[1];
    const float* Ws        = (const float*)d_in[2];
    const float* Wr        = (const float*)d_in[3];
    const float* Wqr_w     = (const float*)d_in[4];
    const float* Wqr_b     = (const float*)d_in[5];
    const float* wa_w      = (const float*)d_in[6];
    const float* wa_b      = (const float*)d_in[7];
    const float* Wh        = (const float*)d_in[8];
    const int* query_rel   = (const int*)d_in[9];
    const int* facts       = (const int*)d_in[10];
    const int* tail_index  = (const int*)d_in[11];

    int N     = in_sizes[0] / DD;   // 200000
    int Rrows = in_sizes[1] / DD;   // 481
    int B     = in_sizes[9];        // 512
    int E     = in_sizes[11];       // 1000000
    int T     = in_sizes[12];       // 100000

    char* ws = (char*)d_ws;
    size_t off = 0;
    auto alloc = [&](size_t bytes) -> void* {
        void* p = ws + off;
        off += (bytes + 255) & ~(size_t)255;
        return p;
    };
    __half* HB  = (__half*)alloc((size_t)N * 256 * 2);      // 102.4 MB
    __half* RB  = (__half*)alloc((size_t)Rrows * 256 * 2);  // 246 KB
    __half* QB  = (__half*)alloc((size_t)B * DD * 2);       // 128 KB
    int* cursor = (int*)alloc((size_t)T * 4);               // 400 KB
    int2* meta  = (int2*)alloc((size_t)T * CAP * 8);        // 51.2 MB
    half_t* WsT  = (half_t*)alloc((size_t)DD * DD * 2);     // 32 KB
    half_t* WrT  = (half_t*)alloc((size_t)DD * DD * 2);
    half_t* WqrT = (half_t*)alloc((size_t)DD * DD * 2);
    half_t* WhT  = (half_t*)alloc((size_t)DD * DD * 2);

    (void)hipMemsetAsync(cursor, 0, (size_t)T * 4, stream);

    // f16 transposed weights (one tiny launch)
    wt4<<<4, 256, 0, stream>>>(Ws, Wr, Wqr_w, Wh, WsT, WrT, WqrT, WhT);

    // HB = {f16(hidden @ Wh) || f16(hidden @ Ws)}   (Wh folded via linearity)
    gemm_pack2<<<(N + 63) / 64, 256, 0, stream>>>(hidden, N, WhT, WsT, HB);
    // RB = {f16(rel_table @ Wh) || f16(rel_table @ Wr)}
    gemm_pack2<<<(Rrows + 63) / 64, 256, 0, stream>>>(rel_table, Rrows, WhT, WrT, RB);
    // QB = f16(rel_table[query_rel+1] @ Wqr_w + Wqr_b)
    gemm_mfma<<<(B + 63) / 64, 256, 0, stream>>>(rel_table, query_rel, 1, B,
                                                 WqrT, Wqr_b, nullptr, QB);

    // alpha + scatter fused: 8 facts/wave, 6 gathers in flight
    alpha_scatter<<<(E + 31) / 32, 256, 0, stream>>>(HB, RB, QB, facts, tail_index,
                                                     wa_w, wa_b, cursor, meta, E);

    // out[t] = sum alpha * (hWh + hrWh)  — final GEMM eliminated by linearity
    agg_out<<<(T + 3) / 4, 256, 0, stream>>>(HB, RB, meta, cursor,
                                             (float*)d_out, T);
}

// Round 6
// 448.164 us; speedup vs baseline: 1.1549x; 1.0078x over previous
//
#include <hip/hip_runtime.h>
#include <hip/hip_fp16.h>
#include <math.h>

#define DD 128
#define CAP 64   // max facts per tail bucket; Poisson(10) => P(overflow) ~ 1e-30

typedef _Float16 half_t;
typedef __attribute__((ext_vector_type(8))) _Float16 half8;
typedef __attribute__((ext_vector_type(4))) float floatx4;

#define LDW 136  // 128 + 8 f16 pad: frag rows land 4 banks apart -> 2-way alias only (free)

// packed relu: x * (x > 0)  — ROCm 7.2 has no __hmax2
__device__ __forceinline__ __half2 relu2(__half2 x) {
    return __hmul2(x, __hgt2(x, __float2half2_rn(0.f)));
}

// DPP-fused add: t += dpp(t, CTRL); pure VALU, no LDS pipe.
template <int CTRL>
__device__ __forceinline__ float dpp_add(float x) {
    int y = __builtin_amdgcn_update_dpp(0, __float_as_int(x), CTRL, 0xf, 0xf, true);
    return x + __int_as_float(y);
}

// ---------------- one-time: W[k][n] f32 -> WT[n][k] f16 (4 matrices) ---------
__global__ void wt4(const float* __restrict__ W0, const float* __restrict__ W1,
                    const float* __restrict__ W2, const float* __restrict__ W3,
                    half_t* __restrict__ T0, half_t* __restrict__ T1,
                    half_t* __restrict__ T2, half_t* __restrict__ T3) {
    const float* W = blockIdx.x == 0 ? W0 : blockIdx.x == 1 ? W1 : blockIdx.x == 2 ? W2 : W3;
    half_t* T      = blockIdx.x == 0 ? T0 : blockIdx.x == 1 ? T1 : blockIdx.x == 2 ? T2 : T3;
    for (int i = threadIdx.x; i < DD * DD; i += blockDim.x) {
        int n = i >> 7, k = i & 127;
        T[i] = (half_t)W[(size_t)k * DD + n];
    }
}

// MFMA tile pass: acc over K=128 from As(row-tile) x WT(col-tile); result left
// in acc[8] (D layout: col = t*16 + (lane&15), row = w*16 + (lane>>4)*4 + i).
__device__ __forceinline__ void mfma_pass(
    const half_t* As, const half_t* WT, int w, int lane, floatx4 acc[8]) {
    int rowf = lane & 15;
    int kgrp = (lane >> 4) * 8;
#pragma unroll
    for (int t = 0; t < 8; t++) acc[t] = (floatx4){0.f, 0.f, 0.f, 0.f};
    const half_t* ap = As + (w * 16 + rowf) * LDW + kgrp;
    const half_t* bp0 = WT + rowf * LDW + kgrp;
#pragma unroll
    for (int kk = 0; kk < DD; kk += 32) {
        half8 a = *(const half8*)(ap + kk);
#pragma unroll
        for (int t = 0; t < 8; t++) {
            half8 b = *(const half8*)(bp0 + t * 16 * LDW + kk);
            acc[t] = __builtin_amdgcn_mfma_f32_16x16x32_f16(a, b, acc[t], 0, 0, 0);
        }
    }
}

// scatter acc into a [64][LDW] f16 LDS tile (scalar ds_write_b16, cheap).
__device__ __forceinline__ void acc_to_lds(const floatx4 acc[8], half_t* OutT,
                                           int w, int lane) {
    int rowf = lane & 15;
    int rbase = w * 16 + (lane >> 4) * 4;
#pragma unroll
    for (int t = 0; t < 8; t++) {
        int col = t * 16 + rowf;
#pragma unroll
        for (int i = 0; i < 4; i++) OutT[(rbase + i) * LDW + col] = (half_t)acc[t][i];
    }
}

// coalesced copy of the [64][128] f16 tile to Packed[gr*256 + halfOff + ...]
__device__ __forceinline__ void lds_to_packed(const half_t* OutT, int tileM, int M,
                                              int tid, __half* Packed, int halfOff) {
    for (int ch = tid; ch < 1024; ch += 256) {   // 64 rows x 16 chunks of 8 halves
        int row = ch >> 4, off = (ch & 15) * 8;
        int gr = tileM + row;
        if (gr < M) {
            half8 v = *(const half8*)(OutT + row * LDW + off);
            *(uint4*)(Packed + (size_t)gr * 256 + halfOff + off) = *(uint4*)&v;
        }
    }
}

// ---------------- MFMA GEMM x2, packed-f16 epilogue --------------------------
// Packed[row] = { f16(A@W1)[0..127] , f16(A@W2)[0..127] }  (512 B/row)
// WT LDS buffer is reused: weights -> then accumulator bounce for coalesced
// uint4 stores (the direct epilogue was 64 scalar 2-B stores per thread).
__global__ __launch_bounds__(256) void gemm_pack2(
    const float* __restrict__ table, int M,
    const half_t* __restrict__ WT1_g, const half_t* __restrict__ WT2_g,
    __half* __restrict__ Packed) {
    __shared__ half_t WT[DD * LDW];     // 34.8 KB (also reused as 64x136 out tile)
    __shared__ half_t As[64 * LDW];     // 17.4 KB
    int tid = threadIdx.x;
    int lane = tid & 63;
    int w = tid >> 6;
    int tileM = blockIdx.x * 64;

    // A tile -> f16 LDS
    for (int i = tid; i < 2048; i += 256) {
        int row = i >> 5, c4 = i & 31;
        int gr = tileM + row;
        float4 v = make_float4(0.f, 0.f, 0.f, 0.f);
        if (gr < M) v = *(const float4*)(table + (size_t)gr * DD + c4 * 4);
        __half2 h01 = __floats2half2_rn(v.x, v.y);
        __half2 h23 = __floats2half2_rn(v.z, v.w);
        *(uint2*)(As + row * LDW + c4 * 4) = make_uint2(*(unsigned*)&h01, *(unsigned*)&h23);
    }
    // WT <- W1
    for (int i = tid; i < 2048; i += 256) {
        int n = i >> 4, ch = i & 15;
        *(half8*)(WT + n * LDW + ch * 8) = *(const half8*)(WT1_g + n * DD + ch * 8);
    }
    __syncthreads();
    floatx4 acc[8];
    mfma_pass(As, WT, w, lane, acc);
    __syncthreads();                    // all waves done reading WT(W1)
    acc_to_lds(acc, WT, w, lane);
    __syncthreads();
    lds_to_packed(WT, tileM, M, tid, Packed, 0);
    __syncthreads();                    // copy-out done before overwriting WT
    // WT <- W2
    for (int i = tid; i < 2048; i += 256) {
        int n = i >> 4, ch = i & 15;
        *(half8*)(WT + n * LDW + ch * 8) = *(const half8*)(WT2_g + n * DD + ch * 8);
    }
    __syncthreads();
    mfma_pass(As, WT, w, lane, acc);
    __syncthreads();
    acc_to_lds(acc, WT, w, lane);
    __syncthreads();
    lds_to_packed(WT, tileM, M, tid, Packed, 128);
}

// ---------------- MFMA GEMM: Out[M x 128] = gather(A) @ W (+bias) ------------
// (only used for the tiny QB pass now; direct epilogue is fine at B=512)
__global__ __launch_bounds__(256) void gemm_mfma(
    const float* __restrict__ table, const int* __restrict__ idx, int idxAdd, int M,
    const half_t* __restrict__ WT_g, const float* __restrict__ bias,
    float* __restrict__ OutF, __half* __restrict__ OutH) {
    __shared__ half_t WT[DD * LDW];
    __shared__ half_t As[64 * LDW];
    int tid = threadIdx.x;
    int lane = tid & 63;
    int w = tid >> 6;
    int rowf = lane & 15;

    for (int i = tid; i < 2048; i += 256) {
        int n = i >> 4, ch = i & 15;
        *(half8*)(WT + n * LDW + ch * 8) = *(const half8*)(WT_g + n * DD + ch * 8);
    }
    int tileM = blockIdx.x * 64;
    for (int i = tid; i < 2048; i += 256) {
        int row = i >> 5, c4 = i & 31;
        int gr = tileM + row;
        float4 v = make_float4(0.f, 0.f, 0.f, 0.f);
        if (gr < M) {
            int src = idx ? (idx[gr] + idxAdd) : gr;
            v = *(const float4*)(table + (size_t)src * DD + c4 * 4);
        }
        __half2 h01 = __floats2half2_rn(v.x, v.y);
        __half2 h23 = __floats2half2_rn(v.z, v.w);
        *(uint2*)(As + row * LDW + c4 * 4) = make_uint2(*(unsigned*)&h01, *(unsigned*)&h23);
    }
    __syncthreads();

    floatx4 acc[8];
    mfma_pass(As, WT, w, lane, acc);
    int orow = tileM + w * 16 + (lane >> 4) * 4;
#pragma unroll
    for (int t = 0; t < 8; t++) {
        int col = t * 16 + rowf;
        float bv = bias ? bias[col] : 0.f;
#pragma unroll
        for (int i = 0; i < 4; i++) {
            int gr = orow + i;
            if (gr < M) {
                float o = acc[t][i] + bv;
                if (OutF) OutF[(size_t)gr * DD + col] = o;
                if (OutH) OutH[(size_t)gr * DD + col] = __float2half(o);
            }
        }
    }
}

// ---------------- fused alpha + scatter over E facts -------------------------
// 16 facts per wave: quarter-wave group g (16 lanes) handles facts e0+g+4j,
// j=0..3; each lane owns 8 cols (one uint4 per table). 12 gather-loads in
// flight per wave. DPP row_shr reduce within 16 lanes -> lane15 holds sum.
// Lane15 computes sigmoid, packs alpha into meta.y high 16 bits, scatters.
__global__ __launch_bounds__(256) void alpha_scatter(
    const __half* __restrict__ HB, const __half* __restrict__ RB,
    const __half* __restrict__ QB, const int* __restrict__ facts,
    const int* __restrict__ tail, const float* __restrict__ wa,
    const float* __restrict__ wa_b,
    int* __restrict__ cursor, int2* __restrict__ meta, int E) {
    int tid = threadIdx.x;
    int lane = tid & 63;
    int g = lane >> 4;       // quarter-wave group 0..3
    int cl = lane & 15;
    int c = cl * 8;          // 8 cols per lane
    int wv = (blockIdx.x * 256 + tid) >> 6;
    int e0 = wv * 16 + g;

    float4 wva = *(const float4*)(wa + c);
    float4 wvb = *(const float4*)(wa + c + 4);
    __half2 w0 = __halves2half2(__float2half(wva.x), __float2half(wva.y));
    __half2 w1 = __halves2half2(__float2half(wva.z), __float2half(wva.w));
    __half2 w2 = __halves2half2(__float2half(wvb.x), __float2half(wvb.y));
    __half2 w3 = __halves2half2(__float2half(wvb.z), __float2half(wvb.w));
    float wb = wa_b[0];

    bool v[4]; int2 bn[4]; int r[4]; int tl[4];
#pragma unroll
    for (int j = 0; j < 4; j++) {
        int f = e0 + j * 4;
        v[j] = f < E;
        int fc = v[j] ? f : 0;
        bn[j] = *(const int2*)(facts + (size_t)fc * 6);   // {b, n}
        r[j] = facts[(size_t)fc * 6 + 3];
        tl[j] = tail[fc];
    }

    // 12 independent 16B gathers in flight
    uint4 h[4], rr[4], q[4];
#pragma unroll
    for (int j = 0; j < 4; j++) {
        h[j]  = *(const uint4*)(HB + (size_t)bn[j].y * 256 + 128 + c);
        rr[j] = *(const uint4*)(RB + (size_t)(r[j] + 1) * 256 + 128 + c);
        q[j]  = *(const uint4*)(QB + (size_t)bn[j].x * DD + c);
    }

    float t[4];
#pragma unroll
    for (int j = 0; j < 4; j++) {
        __half2 p0 = relu2(__hadd2(__hadd2(*(__half2*)&h[j].x, *(__half2*)&rr[j].x),
                                   *(__half2*)&q[j].x));
        __half2 p1 = relu2(__hadd2(__hadd2(*(__half2*)&h[j].y, *(__half2*)&rr[j].y),
                                   *(__half2*)&q[j].y));
        __half2 p2 = relu2(__hadd2(__hadd2(*(__half2*)&h[j].z, *(__half2*)&rr[j].z),
                                   *(__half2*)&q[j].z));
        __half2 p3 = relu2(__hadd2(__hadd2(*(__half2*)&h[j].w, *(__half2*)&rr[j].w),
                                   *(__half2*)&q[j].w));
        __half2 t2 = __hfma2(p1, w1, __hmul2(p0, w0));
        t2 = __hfma2(p2, w2, t2);
        t2 = __hfma2(p3, w3, t2);
        t[j] = __half2float(__low2half(t2)) + __half2float(__high2half(t2));
    }

    // 16-lane row reduce (f32): lane cl==15 of each row holds the sum
#pragma unroll
    for (int j = 0; j < 4; j++) {
        t[j] = dpp_add<0x111>(t[j]);
        t[j] = dpp_add<0x112>(t[j]);
        t[j] = dpp_add<0x114>(t[j]);
        t[j] = dpp_add<0x118>(t[j]);
    }

    if (cl == 15) {
#pragma unroll
        for (int j = 0; j < 4; j++) {
            if (v[j]) {
                float a = 1.f / (1.f + __expf(-(t[j] + wb)));
                unsigned ab = (unsigned)__half_as_ushort(__float2half(a));
                int slot = atomicAdd(&cursor[tl[j]], 1);
                if (slot < CAP)
                    meta[(size_t)tl[j] * CAP + slot] =
                        make_int2(bn[j].y, (r[j] + 1) | (int)(ab << 16));
            }
        }
    }
}

// ---------------- segment aggregation direct to output -----------------------
// out[t] = sum alpha * (hWh[n] + hrWh[r])  — first halves of HB/RB rows.
// one wave per segment, 2 cols/lane, 8 facts in flight per iteration, f32 acc.
__global__ __launch_bounds__(256) void agg_out(
    const __half* __restrict__ HB, const __half* __restrict__ RB,
    const int2* __restrict__ meta, const int* __restrict__ cursor,
    float* __restrict__ out, int T) {
    int w = threadIdx.x >> 6;
    int lane = threadIdx.x & 63;
    int seg = blockIdx.x * 4 + w;
    if (seg >= T) return;
    int cnt = cursor[seg];
    if (cnt > CAP) cnt = CAP;
    const int2* mp = meta + (size_t)seg * CAP;
    int co = lane * 2;
    float ax = 0.f, ay = 0.f;

#define ACC(hu, ru, y_)                                                        \
    {                                                                          \
        __half2 s = __hadd2(*(__half2*)&(hu), *(__half2*)&(ru));               \
        float al =                                                             \
            __half2float(__ushort_as_half((unsigned short)((unsigned)(y_) >> 16))); \
        float2 sf = __half22float2(s);                                         \
        ax = fmaf(al, sf.x, ax);                                               \
        ay = fmaf(al, sf.y, ay);                                               \
    }

    int i = 0;
    for (; i + 7 < cnt; i += 8) {
        int4 ma = *(const int4*)(mp + i);
        int4 mb = *(const int4*)(mp + i + 2);
        int4 mc = *(const int4*)(mp + i + 4);
        int4 md = *(const int4*)(mp + i + 6);
        unsigned h0 = *(const unsigned*)(HB + (size_t)ma.x * 256 + co);
        unsigned r0 = *(const unsigned*)(RB + (size_t)(ma.y & 0xFFFF) * 256 + co);
        unsigned h1 = *(const unsigned*)(HB + (size_t)ma.z * 256 + co);
        unsigned r1 = *(const unsigned*)(RB + (size_t)(ma.w & 0xFFFF) * 256 + co);
        unsigned h2 = *(const unsigned*)(HB + (size_t)mb.x * 256 + co);
        unsigned r2 = *(const unsigned*)(RB + (size_t)(mb.y & 0xFFFF) * 256 + co);
        unsigned h3 = *(const unsigned*)(HB + (size_t)mb.z * 256 + co);
        unsigned r3 = *(const unsigned*)(RB + (size_t)(mb.w & 0xFFFF) * 256 + co);
        unsigned h4 = *(const unsigned*)(HB + (size_t)mc.x * 256 + co);
        unsigned r4 = *(const unsigned*)(RB + (size_t)(mc.y & 0xFFFF) * 256 + co);
        unsigned h5 = *(const unsigned*)(HB + (size_t)mc.z * 256 + co);
        unsigned r5 = *(const unsigned*)(RB + (size_t)(mc.w & 0xFFFF) * 256 + co);
        unsigned h6 = *(const unsigned*)(HB + (size_t)md.x * 256 + co);
        unsigned r6 = *(const unsigned*)(RB + (size_t)(md.y & 0xFFFF) * 256 + co);
        unsigned h7 = *(const unsigned*)(HB + (size_t)md.z * 256 + co);
        unsigned r7 = *(const unsigned*)(RB + (size_t)(md.w & 0xFFFF) * 256 + co);
        ACC(h0, r0, ma.y); ACC(h1, r1, ma.w);
        ACC(h2, r2, mb.y); ACC(h3, r3, mb.w);
        ACC(h4, r4, mc.y); ACC(h5, r5, mc.w);
        ACC(h6, r6, md.y); ACC(h7, r7, md.w);
    }
    for (; i + 3 < cnt; i += 4) {
        int4 ma = *(const int4*)(mp + i);
        int4 mb = *(const int4*)(mp + i + 2);
        unsigned h0 = *(const unsigned*)(HB + (size_t)ma.x * 256 + co);
        unsigned r0 = *(const unsigned*)(RB + (size_t)(ma.y & 0xFFFF) * 256 + co);
        unsigned h1 = *(const unsigned*)(HB + (size_t)ma.z * 256 + co);
        unsigned r1 = *(const unsigned*)(RB + (size_t)(ma.w & 0xFFFF) * 256 + co);
        unsigned h2 = *(const unsigned*)(HB + (size_t)mb.x * 256 + co);
        unsigned r2 = *(const unsigned*)(RB + (size_t)(mb.y & 0xFFFF) * 256 + co);
        unsigned h3 = *(const unsigned*)(HB + (size_t)mb.z * 256 + co);
        unsigned r3 = *(const unsigned*)(RB + (size_t)(mb.w & 0xFFFF) * 256 + co);
        ACC(h0, r0, ma.y); ACC(h1, r1, ma.w);
        ACC(h2, r2, mb.y); ACC(h3, r3, mb.w);
    }
    for (; i < cnt; i++) {
        int2 m = mp[i];
        unsigned hu = *(const unsigned*)(HB + (size_t)m.x * 256 + co);
        unsigned ru = *(const unsigned*)(RB + (size_t)(m.y & 0xFFFF) * 256 + co);
        ACC(hu, ru, m.y);
    }
#undef ACC

    *(float2*)(out + (size_t)seg * DD + co) = make_float2(ax, ay);
}

extern "C" void kernel_launch(void* const* d_in, const int* in_sizes, int n_in,
                              void* d_out, int out_size, void* d_ws, size_t ws_size,
                              hipStream_t stream) {
    const float* hidden    = (const float*)d_in[0];
    const float* rel_table = (const float*)d_in[1];
    const float* Ws        = (const float*)d_in[2];
    const float* Wr        = (const float*)d_in[3];
    const float* Wqr_w     = (const float*)d_in[4];
    const float* Wqr_b     = (const float*)d_in[5];
    const float* wa_w      = (const float*)d_in[6];
    const float* wa_b      = (const float*)d_in[7];
    const float* Wh        = (const float*)d_in[8];
    const int* query_rel   = (const int*)d_in[9];
    const int* facts       = (const int*)d_in[10];
    const int* tail_index  = (const int*)d_in[11];

    int N     = in_sizes[0] / DD;   // 200000
    int Rrows = in_sizes[1] / DD;   // 481
    int B     = in_sizes[9];        // 512
    int E     = in_sizes[11];       // 1000000
    int T     = in_sizes[12];       // 100000

    char* ws = (char*)d_ws;
    size_t off = 0;
    auto alloc = [&](size_t bytes) -> void* {
        void* p = ws + off;
        off += (bytes + 255) & ~(size_t)255;
        return p;
    };
    __half* HB  = (__half*)alloc((size_t)N * 256 * 2);      // 102.4 MB
    __half* RB  = (__half*)alloc((size_t)Rrows * 256 * 2);  // 246 KB
    __half* QB  = (__half*)alloc((size_t)B * DD * 2);       // 128 KB
    int* cursor = (int*)alloc((size_t)T * 4);               // 400 KB
    int2* meta  = (int2*)alloc((size_t)T * CAP * 8);        // 51.2 MB
    half_t* WsT  = (half_t*)alloc((size_t)DD * DD * 2);     // 32 KB
    half_t* WrT  = (half_t*)alloc((size_t)DD * DD * 2);
    half_t* WqrT = (half_t*)alloc((size_t)DD * DD * 2);
    half_t* WhT  = (half_t*)alloc((size_t)DD * DD * 2);

    (void)hipMemsetAsync(cursor, 0, (size_t)T * 4, stream);

    // f16 transposed weights (one tiny launch)
    wt4<<<4, 256, 0, stream>>>(Ws, Wr, Wqr_w, Wh, WsT, WrT, WqrT, WhT);

    // HB = {f16(hidden @ Wh) || f16(hidden @ Ws)}   (Wh folded via linearity)
    gemm_pack2<<<(N + 63) / 64, 256, 0, stream>>>(hidden, N, WhT, WsT, HB);
    // RB = {f16(rel_table @ Wh) || f16(rel_table @ Wr)}
    gemm_pack2<<<(Rrows + 63) / 64, 256, 0, stream>>>(rel_table, Rrows, WhT, WrT, RB);
    // QB = f16(rel_table[query_rel+1] @ Wqr_w + Wqr_b)
    gemm_mfma<<<(B + 63) / 64, 256, 0, stream>>>(rel_table, query_rel, 1, B,
                                                 WqrT, Wqr_b, nullptr, QB);

    // alpha + scatter fused: 16 facts/wave, 12 gathers in flight
    alpha_scatter<<<(E + 63) / 64, 256, 0, stream>>>(HB, RB, QB, facts, tail_index,
                                                     wa_w, wa_b, cursor, meta, E);

    // out[t] = sum alpha * (hWh + hrWh)  — final GEMM eliminated by linearity
    agg_out<<<(T + 3) / 4, 256, 0, stream>>>(HB, RB, meta, cursor,
                                             (float*)d_out, T);
}